// Round 2
// baseline (479.259 us; speedup 1.0000x reference)
//
#include <hip/hip_runtime.h>

// DEMA over x:(B=32, T=4096, F=512) fp32, scan along T.
// Recurrence v_t = A v_{t-1} + c(x_t), A = [[0.7,0.7],[-0.03,0.97]],
// |lambda| = sqrt(0.7) ~ 0.8367 -> ||A^64|| ~ 13*0.8367^64 ~ 1.4e-4:
// a 64-step warmup from a crude local init reproduces the state to ~1e-4 *
// input scale, far below the fp32 accumulation noise (~1.6e-2 measured).
// => time chunks are independent given a 64-row halo; fully parallel kernel.
//
// R1: float4 per thread (1 KB contiguous per wave-load, 4 indep chains),
// C=32 chunks (16 waves/CU), unroll 8 -> up to 8 KB in flight per wave.

#define DEMA_ALPHA 0.3f
#define DEMA_BETA  0.1f
#define DEMA_T     4096
#define DEMA_B     32
#define DEMA_F     512
#define DEMA_L     128               // output chunk length
#define DEMA_H     64                // warmup halo length
#define DEMA_C     (DEMA_T / DEMA_L) // 32 chunks
#define DEMA_F4    (DEMA_F / 4)      // 128 float4 columns

__device__ __forceinline__ void dema_step(const float4 xt, float4& s, float4& bb) {
    const float a1 = 1.0f - DEMA_ALPHA;   // 0.7
    const float b1 = 1.0f - DEMA_BETA;    // 0.9
    float4 sp = s;
    s.x = DEMA_ALPHA * xt.x + a1 * (sp.x + bb.x);
    s.y = DEMA_ALPHA * xt.y + a1 * (sp.y + bb.y);
    s.z = DEMA_ALPHA * xt.z + a1 * (sp.z + bb.z);
    s.w = DEMA_ALPHA * xt.w + a1 * (sp.w + bb.w);
    bb.x = DEMA_BETA * (s.x - sp.x) + b1 * bb.x;
    bb.y = DEMA_BETA * (s.y - sp.y) + b1 * bb.y;
    bb.z = DEMA_BETA * (s.z - sp.z) + b1 * bb.z;
    bb.w = DEMA_BETA * (s.w - sp.w) + b1 * bb.w;
}

__global__ __launch_bounds__(256) void dema_kernel(const float* __restrict__ x,
                                                   float* __restrict__ out) {
    const int fq = threadIdx.x;                       // 0..127 float4-column
    const int b  = blockIdx.y * 2 + threadIdx.y;      // 0..31
    const int c  = blockIdx.z;                        // 0..31 chunk idx

    const int base4 = (b * DEMA_T) * DEMA_F4 + fq;    // float4-element index
    const float4* __restrict__ xp = (const float4*)x + base4;
    float4* __restrict__ op = (float4*)out + base4;

    float4 s, bb;
    if (c == 0) {
        // Exact prefix: s0 = x0 (emitted), b0 = x1 - x0.
        s = xp[0];
        float4 x1 = xp[DEMA_F4];
        bb.x = x1.x - s.x; bb.y = x1.y - s.y; bb.z = x1.z - s.z; bb.w = x1.w - s.w;
        op[0] = s;
        #pragma unroll 8
        for (int t = 1; t < DEMA_L; ++t) {
            float4 xt = xp[t * DEMA_F4];
            dema_step(xt, s, bb);
            op[t * DEMA_F4] = s;
        }
    } else {
        const int t0 = c * DEMA_L;        // >= 128
        const int tw = t0 - DEMA_H;       // >= 64 >= 1
        // Crude local init at tw-1; decays by ||A^64|| ~ 1.4e-4 over warmup.
        s = xp[(tw - 1) * DEMA_F4];
        float4 x1 = xp[tw * DEMA_F4];
        bb.x = x1.x - s.x; bb.y = x1.y - s.y; bb.z = x1.z - s.z; bb.w = x1.w - s.w;
        #pragma unroll 8
        for (int t = tw; t < t0; ++t) {   // warmup, no writes
            float4 xt = xp[t * DEMA_F4];
            dema_step(xt, s, bb);
        }
        #pragma unroll 8
        for (int t = t0; t < t0 + DEMA_L; ++t) {
            float4 xt = xp[t * DEMA_F4];
            dema_step(xt, s, bb);
            op[t * DEMA_F4] = s;
        }
    }
}

extern "C" void kernel_launch(void* const* d_in, const int* in_sizes, int n_in,
                              void* d_out, int out_size, void* d_ws, size_t ws_size,
                              hipStream_t stream) {
    const float* x = (const float*)d_in[0];
    float* out = (float*)d_out;

    dim3 block(DEMA_F4, 2, 1);                 // 128 x 2 = 256 threads
    dim3 grid(1, DEMA_B / 2, DEMA_C);          // (1, 16, 32) = 512 blocks
    dema_kernel<<<grid, block, 0, stream>>>(x, out);
}

// Round 3
// 471.190 us; speedup vs baseline: 1.0171x; 1.0171x over previous
//
#include <hip/hip_runtime.h>

// DEMA over x:(B=32, T=4096, F=512) fp32, scan along T.
// v_t = A v_{t-1} + c(x_t), A = [[0.7,0.7],[-0.03,0.97]], |lambda|=sqrt(0.7)
// ~0.8367 -> ||A^64|| ~ 13*0.8367^64 ~ 1.4e-4: 64-step warmup from a crude
// local init reproduces state to ~1e-4, far below fp32 noise (~0.03 measured).
// => time chunks independent given a 64-row halo; fully parallel kernel.
//
// R2: explicit double-buffered 8-group prefetch (forces 8 KB/wave in flight;
// R1's VGPR=36 proved the compiler wasn't pipelining), C=64 chunks -> 16
// waves/CU, non-temporal stores (out never re-read; keep L3 for x halo).

#define DEMA_ALPHA 0.3f
#define DEMA_BETA  0.1f
#define DEMA_T     4096
#define DEMA_B     32
#define DEMA_F     512
#define DEMA_L     64                // output chunk length
#define DEMA_H     64                // warmup halo length
#define DEMA_C     (DEMA_T / DEMA_L) // 64 chunks
#define DEMA_F4    (DEMA_F / 4)      // 128 float4 columns
#define DEMA_G     8                 // pipeline group size

typedef float vfloat4 __attribute__((ext_vector_type(4)));

__device__ __forceinline__ void dema_step(const float4 xt, float4& s, float4& bb) {
    const float a1 = 1.0f - DEMA_ALPHA;   // 0.7
    const float b1 = 1.0f - DEMA_BETA;    // 0.9
    float4 sp = s;
    s.x = DEMA_ALPHA * xt.x + a1 * (sp.x + bb.x);
    s.y = DEMA_ALPHA * xt.y + a1 * (sp.y + bb.y);
    s.z = DEMA_ALPHA * xt.z + a1 * (sp.z + bb.z);
    s.w = DEMA_ALPHA * xt.w + a1 * (sp.w + bb.w);
    bb.x = DEMA_BETA * (s.x - sp.x) + b1 * bb.x;
    bb.y = DEMA_BETA * (s.y - sp.y) + b1 * bb.y;
    bb.z = DEMA_BETA * (s.z - sp.z) + b1 * bb.z;
    bb.w = DEMA_BETA * (s.w - sp.w) + b1 * bb.w;
}

__device__ __forceinline__ void nt_store(float4* p, const float4 v) {
    __builtin_nontemporal_store(*(const vfloat4*)&v, (vfloat4*)p);
}

__global__ __launch_bounds__(256, 4) void dema_kernel(const float* __restrict__ x,
                                                      float* __restrict__ out) {
    const int fq = threadIdx.x;                       // 0..127 float4-column
    const int b  = blockIdx.y * 2 + threadIdx.y;      // 0..31
    const int c  = blockIdx.z;                        // 0..63 chunk idx

    const int base4 = (b * DEMA_T) * DEMA_F4 + fq;
    const float4* __restrict__ xp = (const float4*)x + base4;
    float4* __restrict__ op = (float4*)out + base4;

    float4 s, bb;

    if (c == 0) {
        // Exact prefix: s0 = x0 (emitted), b0 = x1 - x0. Only 32/2048 blocks;
        // simple loop is fine.
        s = xp[0];
        float4 x1 = xp[DEMA_F4];
        bb.x = x1.x - s.x; bb.y = x1.y - s.y; bb.z = x1.z - s.z; bb.w = x1.w - s.w;
        nt_store(&op[0], s);
        #pragma unroll 8
        for (int t = 1; t < DEMA_L; ++t) {
            float4 xt = xp[t * DEMA_F4];
            dema_step(xt, s, bb);
            nt_store(&op[t * DEMA_F4], s);
        }
        return;
    }

    const int t0 = c * DEMA_L;
    const int tw = t0 - DEMA_H;      // >= 0
    if (tw == 0) {
        // c==1: exact s-init at t=0 with b=0; b-error decays by ||A^63||.
        s = xp[0];
        bb.x = 0.f; bb.y = 0.f; bb.z = 0.f; bb.w = 0.f;
    } else {
        s = xp[(tw - 1) * DEMA_F4];
        float4 x1 = xp[tw * DEMA_F4];
        bb.x = x1.x - s.x; bb.y = x1.y - s.y; bb.z = x1.z - s.z; bb.w = x1.w - s.w;
    }

    // Double-buffered pipeline over NG = (H+L)/G = 16 groups of G=8 steps.
    // Fully unrolled so buf indices are compile-time (no scratch spill).
    const int NG  = (DEMA_H + DEMA_L) / DEMA_G;   // 16
    const int NGW = DEMA_H / DEMA_G;              // 8 warmup groups

    float4 buf[2][DEMA_G];
    #pragma unroll
    for (int j = 0; j < DEMA_G; ++j)
        buf[0][j] = xp[(tw + j) * DEMA_F4];

    #pragma unroll
    for (int g = 0; g < NG; ++g) {
        const int cur = g & 1;
        const int tg  = tw + g * DEMA_G;
        if (g + 1 < NG) {
            #pragma unroll
            for (int j = 0; j < DEMA_G; ++j)
                buf[cur ^ 1][j] = xp[(tg + DEMA_G + j) * DEMA_F4];
        }
        if (g < NGW) {
            #pragma unroll
            for (int j = 0; j < DEMA_G; ++j)
                dema_step(buf[cur][j], s, bb);
        } else {
            #pragma unroll
            for (int j = 0; j < DEMA_G; ++j) {
                dema_step(buf[cur][j], s, bb);
                nt_store(&op[(tg + j) * DEMA_F4], s);
            }
        }
    }
}

extern "C" void kernel_launch(void* const* d_in, const int* in_sizes, int n_in,
                              void* d_out, int out_size, void* d_ws, size_t ws_size,
                              hipStream_t stream) {
    const float* x = (const float*)d_in[0];
    float* out = (float*)d_out;

    dim3 block(DEMA_F4, 2, 1);                 // 128 x 2 = 256 threads
    dim3 grid(1, DEMA_B / 2, DEMA_C);          // (1, 16, 64) = 1024 blocks
    dema_kernel<<<grid, block, 0, stream>>>(x, out);
}